// Round 2
// baseline (727.621 us; speedup 1.0000x reference)
//
#include <hip/hip_runtime.h>

#define TT 512
#define BB 256
#define DD 128
#define HH 128
#define QQ 8

struct Params {
    const float* x;
    const float* W[4];
    const float* b[4];
    const float* th[4];
    const float* U[4];
    const float* cb[4];
    float* out;
};

// One block per batch element. 256 threads = 4 waves; wave w owns gate w
// (order f,i,g,o). Thread = (gate=wv, qubit=(tid>>3)&7, part=tid&7).
// LDS pad: slot(k) = k + 4*(k>>5) -> conflict-free + 16B-aligned b128 reads.
__global__ __launch_bounds__(256, 1) void qlstm(Params p) {
    __shared__ __align__(16) float xbuf[2][8][144]; // staged x rows (padded)
    __shared__ __align__(16) float hbuf[144];       // h_{t-1} (padded)
    __shared__ float pre[512];                      // gate preactivations

    const int tid = threadIdx.x;
    const int bId = blockIdx.x;
    const int ln  = tid & 63;        // lane in wave
    const int wv  = tid >> 6;        // wave id == gate id
    const int qub = (tid >> 3) & 7;  // qubit
    const int part = tid & 7;        // k-slice

    // ---- constant per-thread registers ----
    float Wreg[32];
    {
        const float* Wg = p.W[wv] + qub * (DD + HH) + part * 32;
        #pragma unroll
        for (int j = 0; j < 32; ++j) Wreg[j] = Wg[j];
    }
    const float breg  = p.b[wv][qub];
    const float threg = p.th[wv][qub];

    // U-phase: wave wv computes gate wv preacts for h0=ln, h1=ln+64
    float Ua[8], Ub[8];
    #pragma unroll
    for (int j = 0; j < 8; ++j) {
        Ua[j] = p.U[wv][ln * QQ + j];
        Ub[j] = p.U[wv][(ln + 64) * QQ + j];
    }
    const float cba = p.cb[wv][ln];
    const float cbb = p.cb[wv][ln + 64];

    float cst = 0.f;  // cell state, owned by tid<128 (h=tid)

    if (tid < 128) hbuf[tid + 4 * (tid >> 5)] = 0.f;

    // ---- x chunk staging: wave 3. Lane covers col=(ln&31)*4, rows 2j+(ln>>5) ----
    const int xc_col  = (ln & 31) * 4;   // 0..124, step 4
    const int xc_half = ln >> 5;         // 0/1
    const int xc_slot = xc_col + 4 * (xc_col >> 5);
    float4 xr[4];
    #pragma unroll
    for (int j = 0; j < 4; ++j) xr[j] = make_float4(0.f, 0.f, 0.f, 0.f);

    if (wv == 3) {
        // chunk 0 (steps 0..7) -> xbuf[0], synchronous
        #pragma unroll
        for (int j = 0; j < 4; ++j) {
            const int row = 2 * j + xc_half;
            float4 v = *(const float4*)(p.x + ((size_t)row * BB + bId) * DD + xc_col);
            *(float4*)&xbuf[0][row][xc_slot] = v;
        }
        // issue chunk 1 (steps 8..15), consumed at E of step 7
        #pragma unroll
        for (int j = 0; j < 4; ++j) {
            const int row = 8 + 2 * j + xc_half;
            xr[j] = *(const float4*)(p.x + ((size_t)row * BB + bId) * DD + xc_col);
        }
    }
    __syncthreads();

    for (int t = 0; t < TT; ++t) {
        // ---- Z: z[g][q] = W[g][q] . [x_t, h_{t-1}]  (8x b128 + 32 FMA) ----
        const float* src = (part < 4) ? &xbuf[(t >> 3) & 1][t & 7][36 * part]
                                      : &hbuf[36 * (part - 4)];
        float acc = 0.f;
        #pragma unroll
        for (int j4 = 0; j4 < 8; ++j4) {
            float4 c4 = *(const float4*)(src + 4 * j4);
            acc += Wreg[4*j4+0]*c4.x + Wreg[4*j4+1]*c4.y
                 + Wreg[4*j4+2]*c4.z + Wreg[4*j4+3]*c4.w;
        }
        acc += __shfl_xor(acc, 1);
        acc += __shfl_xor(acc, 2);
        acc += __shfl_xor(acc, 4);

        // ---- Qgate: all in-register, stride-8 product scans over lanes ----
        float cv = cosf(acc + breg + threg);   // all 8 lanes of qubit group hold c_q
        float v = cv;                  // inclusive cumprod (with c0)
        float u = (ln < 8) ? 1.f : cv; // cumprod excluding qubit 0
        float r;
        r = __shfl_up(v, 8);  v *= (ln >= 8)  ? r : 1.f;
        r = __shfl_up(u, 8);  u *= (ln >= 8)  ? r : 1.f;
        r = __shfl_up(v, 16); v *= (ln >= 16) ? r : 1.f;
        r = __shfl_up(u, 16); u *= (ln >= 16) ? r : 1.f;
        r = __shfl_up(v, 32); v *= (ln >= 32) ? r : 1.f;
        r = __shfl_up(u, 32); u *= (ln >= 32) ? r : 1.f;
        const float q0 = __shfl(u, 56);   // prod_{j>=1} c_j
        const float q1 = __shfl(v, 8);
        const float q2 = __shfl(v, 16);
        const float q3 = __shfl(v, 24);
        const float q4 = __shfl(v, 32);
        const float q5 = __shfl(v, 40);
        const float q6 = __shfl(v, 48);
        const float q7 = __shfl(v, 56);

        // ---- U expansion: pre[gate][h] ----
        float pa = cba + Ua[0]*q0 + Ua[1]*q1 + Ua[2]*q2 + Ua[3]*q3
                       + Ua[4]*q4 + Ua[5]*q5 + Ua[6]*q6 + Ua[7]*q7;
        float pb = cbb + Ub[0]*q0 + Ub[1]*q1 + Ub[2]*q2 + Ub[3]*q3
                       + Ub[4]*q4 + Ub[5]*q5 + Ub[6]*q6 + Ub[7]*q7;
        pre[wv * 128 + ln]      = pa;
        pre[wv * 128 + 64 + ln] = pb;

        // issue next x chunk (8 steps ahead)
        if (((t & 7) == 0) && wv == 3) {
            const int tch = (t >> 3) + 1;
            if (tch < TT / 8) {
                #pragma unroll
                for (int j = 0; j < 4; ++j) {
                    const int row = tch * 8 + 2 * j + xc_half;
                    xr[j] = *(const float4*)(p.x + ((size_t)row * BB + bId) * DD + xc_col);
                }
            }
        }
        __syncthreads();   // barrier 1: pre[] ready

        // ---- E: cell update (waves 0-1), x LDS write (wave 3) ----
        if (tid < 128) {
            float fg = 1.f / (1.f + expf(-pre[tid]));
            float ig = 1.f / (1.f + expf(-pre[128 + tid]));
            float gg = tanhf(pre[256 + tid]);
            float og = 1.f / (1.f + expf(-pre[384 + tid]));
            cst = fg * cst + ig * gg;
            float hn = og * tanhf(cst);
            hbuf[tid + 4 * (tid >> 5)] = hn;
            p.out[(size_t)(t * BB + bId) * HH + tid] = hn;
            if (t == TT - 1) {
                p.out[(size_t)TT * BB * HH + (size_t)bId * HH + tid] = hn;
                p.out[(size_t)TT * BB * HH + (size_t)BB * HH + (size_t)bId * HH + tid] = cst;
            }
        } else if (wv == 3 && (t & 7) == 7) {
            const int tch = (t >> 3) + 1;
            if (tch < TT / 8) {
                #pragma unroll
                for (int j = 0; j < 4; ++j) {
                    const int row = 2 * j + xc_half;
                    *(float4*)&xbuf[tch & 1][row][xc_slot] = xr[j];
                }
            }
        }
        __syncthreads();   // barrier 2: hbuf / xbuf ready for next step
    }
}

extern "C" void kernel_launch(void* const* d_in, const int* in_sizes, int n_in,
                              void* d_out, int out_size, void* d_ws, size_t ws_size,
                              hipStream_t stream) {
    (void)in_sizes; (void)n_in; (void)out_size; (void)d_ws; (void)ws_size;
    Params p;
    p.x = (const float*)d_in[0];
    for (int g = 0; g < 4; ++g) {
        p.W[g]  = (const float*)d_in[1 + 5 * g + 0];
        p.b[g]  = (const float*)d_in[1 + 5 * g + 1];
        p.th[g] = (const float*)d_in[1 + 5 * g + 2];
        p.U[g]  = (const float*)d_in[1 + 5 * g + 3];
        p.cb[g] = (const float*)d_in[1 + 5 * g + 4];
    }
    p.out = (float*)d_out;
    hipLaunchKernelGGL(qlstm, dim3(BB), dim3(256), 0, stream, p);
}

// Round 3
// 404.490 us; speedup vs baseline: 1.7989x; 1.7989x over previous
//
#include <hip/hip_runtime.h>

#define TT 512
#define BB 256
#define DD 128
#define HH 128
#define QQ 8

struct Params {
    const float* x;
    const float* W[4];
    const float* b[4];
    const float* th[4];
    const float* U[4];
    const float* cb[4];
    float* out;
};

__device__ __forceinline__ float sigm_fast(float x) {
    return __builtin_amdgcn_rcpf(1.f + __expf(-x));
}
__device__ __forceinline__ float tanh_fast(float x) {
    // 1 - 2/(e^{2x}+1); saturates correctly at +-inf
    return 1.f - 2.f * __builtin_amdgcn_rcpf(__expf(2.f * x) + 1.f);
}
template<int CTRL>
__device__ __forceinline__ float dpp_mov(float x) {
    int r = __builtin_amdgcn_update_dpp(0, __float_as_int(x), CTRL, 0xF, 0xF, true);
    return __int_as_float(r);
}

// One block per batch element. 256 threads = 4 waves; wave w owns gate w
// (order f,i,g,o). Thread = (gate=wv, qubit=(tid>>3)&7, part=tid&7).
// LDS pad: slot(k) = k + 4*(k>>5) -> conflict-free + 16B-aligned b128 reads.
__global__ __launch_bounds__(256, 1) void qlstm(Params p) {
    __shared__ __align__(16) float xbuf[2][8][144]; // staged x rows (padded)
    __shared__ __align__(16) float hbuf[144];       // h_{t-1} (padded)
    __shared__ float pre[512];                      // gate preactivations

    const int tid = threadIdx.x;
    const int bId = blockIdx.x;
    const int ln  = tid & 63;        // lane in wave
    const int wv  = tid >> 6;        // wave id == gate id
    const int qub = (tid >> 3) & 7;  // qubit
    const int part = tid & 7;        // k-slice

    // ---- constant per-thread registers ----
    float Wreg[32];
    {
        const float* Wg = p.W[wv] + qub * (DD + HH) + part * 32;
        #pragma unroll
        for (int j = 0; j < 32; ++j) Wreg[j] = Wg[j];
    }
    const float breg  = p.b[wv][qub] + p.th[wv][qub];  // fused bias+theta

    // U-phase: wave wv computes gate wv preacts for h0=ln, h1=ln+64
    float Ua[8], Ub[8];
    #pragma unroll
    for (int j = 0; j < 8; ++j) {
        Ua[j] = p.U[wv][ln * QQ + j];
        Ub[j] = p.U[wv][(ln + 64) * QQ + j];
    }
    const float cba = p.cb[wv][ln];
    const float cbb = p.cb[wv][ln + 64];

    float cst = 0.f;      // cell state, owned by tid<128 (h=tid)
    float hn_last = 0.f;  // last h, kept in-register for the tail stores

    if (tid < 128) hbuf[tid + 4 * (tid >> 5)] = 0.f;

    // ---- x chunk staging: wave 3. Lane covers col=(ln&31)*4, rows 2j+(ln>>5) ----
    const int xc_col  = (ln & 31) * 4;   // 0..124, step 4
    const int xc_half = ln >> 5;         // 0/1
    const int xc_slot = xc_col + 4 * (xc_col >> 5);
    float4 xr[4];
    #pragma unroll
    for (int j = 0; j < 4; ++j) xr[j] = make_float4(0.f, 0.f, 0.f, 0.f);

    if (wv == 3) {
        // chunk 0 (steps 0..7) -> xbuf[0], synchronous
        #pragma unroll
        for (int j = 0; j < 4; ++j) {
            const int row = 2 * j + xc_half;
            float4 v = *(const float4*)(p.x + ((size_t)row * BB + bId) * DD + xc_col);
            *(float4*)&xbuf[0][row][xc_slot] = v;
        }
        // issue chunk 1 (steps 8..15), consumed at E of step 7
        #pragma unroll
        for (int j = 0; j < 4; ++j) {
            const int row = 8 + 2 * j + xc_half;
            xr[j] = *(const float4*)(p.x + ((size_t)row * BB + bId) * DD + xc_col);
        }
    }
    __syncthreads();

    for (int t = 0; t < TT; ++t) {
        // ---- step top: issue long-latency ops with max distance to barrier1 ----
        // next x chunk (8 steps ahead), wave 3
        if (((t & 7) == 0) && wv == 3) {
            const int tch = (t >> 3) + 1;
            if (tch < TT / 8) {
                #pragma unroll
                for (int j = 0; j < 4; ++j) {
                    const int row = tch * 8 + 2 * j + xc_half;
                    xr[j] = *(const float4*)(p.x + ((size_t)row * BB + bId) * DD + xc_col);
                }
            }
        }
        // out[t-1] store by waves 2-3 (off the E critical path; drains during Z)
        if (tid >= 128 && t > 0) {
            const int sid = tid - 128;
            float hv = hbuf[sid + 4 * (sid >> 5)];
            p.out[(size_t)((t - 1) * BB + bId) * HH + sid] = hv;
        }

        // ---- Z: z[g][q] = W[g][q] . [x_t, h_{t-1}]  (8x b128, 4-acc FMA) ----
        const float* src = (part < 4) ? &xbuf[(t >> 3) & 1][t & 7][36 * part]
                                      : &hbuf[36 * (part - 4)];
        float a0 = 0.f, a1 = 0.f, a2 = 0.f, a3 = 0.f;
        #pragma unroll
        for (int j4 = 0; j4 < 8; ++j4) {
            float4 c4 = *(const float4*)(src + 4 * j4);
            a0 = fmaf(Wreg[4*j4+0], c4.x, a0);
            a1 = fmaf(Wreg[4*j4+1], c4.y, a1);
            a2 = fmaf(Wreg[4*j4+2], c4.z, a2);
            a3 = fmaf(Wreg[4*j4+3], c4.w, a3);
        }
        float acc = (a0 + a1) + (a2 + a3);

        // 8-lane reduction via DPP butterflies (VALU speed, no DS)
        acc += dpp_mov<0xB1>(acc);    // quad_perm(1,0,3,2): xor 1
        acc += dpp_mov<0x4E>(acc);    // quad_perm(2,3,0,1): xor 2
        acc += dpp_mov<0x141>(acc);   // row_half_mirror:    xor 4 (within 8)

        // ---- Qgate: cos, single bpermute round, local cumprods ----
        const float cv = __cosf(acc + breg);   // all 8 lanes of octet hold c_q
        float c[8];
        #pragma unroll
        for (int j = 0; j < 8; ++j) {
            c[j] = __int_as_float(
                __builtin_amdgcn_ds_bpermute(j * 32, __float_as_int(cv)));
        }
        const float q1 = c[0] * c[1];
        const float q2 = q1 * c[2];
        const float q3 = q2 * c[3];
        const float q4 = q3 * c[4];
        const float q5 = q4 * c[5];
        const float q6 = q5 * c[6];
        const float q7 = q6 * c[7];
        float q0 = c[1] * c[2];
        q0 *= c[3]; q0 *= c[4]; q0 *= c[5]; q0 *= c[6]; q0 *= c[7];

        // ---- U expansion: pre[gate][h] ----
        float pa = fmaf(Ua[0], q0, cba); float pb = fmaf(Ub[0], q0, cbb);
        pa = fmaf(Ua[1], q1, pa);        pb = fmaf(Ub[1], q1, pb);
        pa = fmaf(Ua[2], q2, pa);        pb = fmaf(Ub[2], q2, pb);
        pa = fmaf(Ua[3], q3, pa);        pb = fmaf(Ub[3], q3, pb);
        pa = fmaf(Ua[4], q4, pa);        pb = fmaf(Ub[4], q4, pb);
        pa = fmaf(Ua[5], q5, pa);        pb = fmaf(Ub[5], q5, pb);
        pa = fmaf(Ua[6], q6, pa);        pb = fmaf(Ub[6], q6, pb);
        pa = fmaf(Ua[7], q7, pa);        pb = fmaf(Ub[7], q7, pb);
        pre[wv * 128 + ln]      = pa;
        pre[wv * 128 + 64 + ln] = pb;

        __syncthreads();   // barrier 1: pre[] ready

        // ---- E: cell update (waves 0-1), x LDS write (wave 3) ----
        if (tid < 128) {
            float fg = sigm_fast(pre[tid]);
            float ig = sigm_fast(pre[128 + tid]);
            float gg = tanh_fast(pre[256 + tid]);
            float og = sigm_fast(pre[384 + tid]);
            cst = fmaf(fg, cst, ig * gg);
            float hn = og * tanh_fast(cst);
            hn_last = hn;
            hbuf[tid + 4 * (tid >> 5)] = hn;
        } else if (wv == 3 && (t & 7) == 7) {
            const int tch = (t >> 3) + 1;
            if (tch < TT / 8) {
                #pragma unroll
                for (int j = 0; j < 4; ++j) {
                    const int row = 2 * j + xc_half;
                    *(float4*)&xbuf[tch & 1][row][xc_slot] = xr[j];
                }
            }
        }
        __syncthreads();   // barrier 2: hbuf / xbuf ready for next step
    }

    // ---- tail: out[511], hx, cx (off the per-step path) ----
    if (tid < 128) {
        p.out[(size_t)((TT - 1) * BB + bId) * HH + tid] = hn_last;
        p.out[(size_t)TT * BB * HH + (size_t)bId * HH + tid] = hn_last;
        p.out[(size_t)TT * BB * HH + (size_t)BB * HH + (size_t)bId * HH + tid] = cst;
    }
}

extern "C" void kernel_launch(void* const* d_in, const int* in_sizes, int n_in,
                              void* d_out, int out_size, void* d_ws, size_t ws_size,
                              hipStream_t stream) {
    (void)in_sizes; (void)n_in; (void)out_size; (void)d_ws; (void)ws_size;
    Params p;
    p.x = (const float*)d_in[0];
    for (int g = 0; g < 4; ++g) {
        p.W[g]  = (const float*)d_in[1 + 5 * g + 0];
        p.b[g]  = (const float*)d_in[1 + 5 * g + 1];
        p.th[g] = (const float*)d_in[1 + 5 * g + 2];
        p.U[g]  = (const float*)d_in[1 + 5 * g + 3];
        p.cb[g] = (const float*)d_in[1 + 5 * g + 4];
    }
    p.out = (float*)d_out;
    hipLaunchKernelGGL(qlstm, dim3(BB), dim3(256), 0, stream, p);
}